// Round 2
// baseline (334.533 us; speedup 1.0000x reference)
//
#include <hip/hip_runtime.h>

// Sparse COO (32x64, nnz=3) @ dense x (64, N) -> out (32, N), fp32.
// Memory-bound: must write all 128 MB of out (harness poisons it), read ~12 MB of x.
// Floor: ~140 MB / 6.6 TB/s ~= 21 us of device time for our kernel.
//
// Fast path (nnz==3): one thread per float4 column-chunk computes ALL 32 output
// rows. Metadata (rows/cols/values) read once per thread; the 3 touched x-rows
// are loaded once (3 float4) and reused across all 32 row-stores (512 B of
// coalesced stores per thread). Branchless row matching via select+FMA, so
// duplicate COO entries accumulate correctly.

#define OUTF 32

__global__ __launch_bounds__(256) void spmm_nnz3(
    const float4* __restrict__ x4,      // (64, ncols4) as float4
    const float* __restrict__ values,   // (3,)
    const int* __restrict__ rows,       // (3,)
    const int* __restrict__ cols,       // (3,)
    float4* __restrict__ out4,          // (32, ncols4) as float4
    int ncols4)
{
    int c4 = blockIdx.x * blockDim.x + threadIdx.x;
    if (c4 >= ncols4) return;

    const int   r0 = rows[0],  r1 = rows[1],  r2 = rows[2];
    const float v0 = values[0], v1 = values[1], v2 = values[2];

    const float4 x0 = x4[(size_t)cols[0] * ncols4 + c4];
    const float4 x1 = x4[(size_t)cols[1] * ncols4 + c4];
    const float4 x2 = x4[(size_t)cols[2] * ncols4 + c4];

    size_t o = (size_t)c4;
    #pragma unroll
    for (int r = 0; r < OUTF; ++r) {
        // per-lane uniform selects; duplicates in rows[] sum correctly
        const float a = (r == r0) ? v0 : 0.f;
        const float b = (r == r1) ? v1 : 0.f;
        const float c = (r == r2) ? v2 : 0.f;
        float4 ov;
        ov.x = a * x0.x + b * x1.x + c * x2.x;
        ov.y = a * x0.y + b * x1.y + c * x2.y;
        ov.z = a * x0.z + b * x1.z + c * x2.z;
        ov.w = a * x0.w + b * x1.w + c * x2.w;
        out4[o] = ov;
        o += (size_t)ncols4;
    }
}

// Generic fallback: blockIdx.y = row (wave-uniform branch), any nnz, any ncols.
__global__ __launch_bounds__(256) void spmm_coo_scalar(
    const float* __restrict__ x,
    const float* __restrict__ values,
    const int* __restrict__ rows,
    const int* __restrict__ cols,
    float* __restrict__ out,
    int ncols, int nnz)
{
    int c = blockIdx.x * blockDim.x + threadIdx.x;
    if (c >= ncols) return;
    int r = blockIdx.y;

    float acc = 0.f;
    for (int k = 0; k < nnz; ++k) {
        if (rows[k] == r) {
            acc += values[k] * x[(long long)cols[k] * ncols + c];
        }
    }
    out[(long long)r * ncols + c] = acc;
}

extern "C" void kernel_launch(void* const* d_in, const int* in_sizes, int n_in,
                              void* d_out, int out_size, void* d_ws, size_t ws_size,
                              hipStream_t stream) {
    const float* x      = (const float*)d_in[0];
    const float* values = (const float*)d_in[1];
    const int*   rows   = (const int*)d_in[2];
    const int*   cols   = (const int*)d_in[3];
    float* out = (float*)d_out;

    const int nnz   = in_sizes[1];
    const int ncols = out_size / OUTF;   // 1,000,000

    if (nnz == 3 && (ncols & 3) == 0) {
        const int ncols4 = ncols >> 2;   // 250,000 float4 per row
        dim3 block(256);
        dim3 grid((ncols4 + 255) / 256);
        spmm_nnz3<<<grid, block, 0, stream>>>(
            (const float4*)x, values, rows, cols, (float4*)out, ncols4);
    } else {
        dim3 block(256);
        dim3 grid((ncols + 255) / 256, OUTF);
        spmm_coo_scalar<<<grid, block, 0, stream>>>(
            x, values, rows, cols, out, ncols, nnz);
    }
}